// Round 7
// baseline (540.245 us; speedup 1.0000x reference)
//
#include <hip/hip_runtime.h>
#include <hip/hip_bf16.h>

#define B_ 128
#define L_ 2048
#define D_ 256
#define H_ 512
#define U_ 256

typedef _Float16 half8 __attribute__((ext_vector_type(8)));
typedef float f32x4 __attribute__((ext_vector_type(4)));

// async global->LDS, 16B per lane: LDS dest = uniform base + lane*16,
// global src = per-lane pointer (base + lane*16 here).
__device__ __forceinline__ void gll16(const void* gsrc, void* lds) {
  __builtin_amdgcn_global_load_lds(
      (const __attribute__((address_space(1))) unsigned int*)gsrc,
      (__attribute__((address_space(3))) unsigned int*)lds, 16, 0, 0);
}

// ---------------------------------------------------------------------------
// Kernel P: W1 [D][U] fp32 -> slot-major split halves W1s[slot=k/8][u][k%8]
// x = hi + lo, 22 effective mantissa bits. Chunk t of the GEMM reads slots
// 4t..4t+3 = one contiguous 16 KB region per half.
// ---------------------------------------------------------------------------
__global__ __launch_bounds__(256) void kp_w1split(
    const float* __restrict__ W1, _Float16* __restrict__ hi,
    _Float16* __restrict__ lo) {
  int slot = blockIdx.x;  // D_/8 = 32
  int u = threadIdx.x;
  union { _Float16 h[8]; float4 f; } H, Lo;
#pragma unroll
  for (int j = 0; j < 8; ++j) {
    float x = W1[(slot * 8 + j) * U_ + u];
    _Float16 h = (_Float16)x;
    H.h[j] = h;
    Lo.h[j] = (_Float16)(x - (float)h);
  }
  *(float4*)&hi[((size_t)slot * U_ + u) * 8] = H.f;
  *(float4*)&lo[((size_t)slot * U_ + u) * 8] = Lo.f;
}

// ---------------------------------------------------------------------------
// Kernel A: ph[b][u] = b1[u] + b2[u] + sum_k hidden[b][k] * W2[k][u]
// ---------------------------------------------------------------------------
__global__ __launch_bounds__(256) void ka_proj_h(
    const float* __restrict__ hidden, const float* __restrict__ W2,
    const float* __restrict__ b1, const float* __restrict__ b2,
    float* __restrict__ ph) {
  int b = blockIdx.x;
  int u = threadIdx.x;
  __shared__ float hs[H_];
  for (int k = u; k < H_; k += 256) hs[k] = hidden[b * H_ + k];
  __syncthreads();
  float acc = b1[u] + b2[u];
#pragma unroll 8
  for (int k = 0; k < H_; ++k) acc += hs[k] * W2[k * U_ + u];
  ph[b * U_ + u] = acc;
}

// ---------------------------------------------------------------------------
// Kernel B (MFMA, 2-phase): logits = sum_u tanh(F·W1 + ph) * V
// Tile 64 rows x 256 cols, 4 waves (wave w owns cols w*64..+63, M-rep 4).
// LDS slot-major [g][row][8 halves]: for any ds access, 8 consecutive lanes
// hit bank quads 0,4,..,28 exactly once -> conflict-free.
// B staged by global_load_lds (double-buffered); A reg-staged early (T14),
// converted fp32->fp16 hi/lo and written after the barrier.
// ---------------------------------------------------------------------------
#define TLM 64
#define BKC 32
#define NCH (D_ / BKC)  // 8 chunks

__global__ __launch_bounds__(256, 2) void kb_mfma(
    const float* __restrict__ features, const _Float16* __restrict__ W1s_hi,
    const _Float16* __restrict__ W1s_lo, const float* __restrict__ ph,
    const float* __restrict__ V, float* __restrict__ logits) {
  __shared__ __align__(16) _Float16 Ah[4][TLM][8], Al[4][TLM][8];   // 8 KB
  __shared__ __align__(16) _Float16 Bh[2][4][U_][8], Bl[2][4][U_][8];  // 64 KB
  __shared__ float red[4][TLM];  // 1 KB

  const int tid = threadIdx.x;
  const int w = tid >> 6;
  const int lane = tid & 63;
  const int g = lane >> 4;   // k-slot of fragment
  const int c = lane & 15;   // row/col within fragment
  const int b = blockIdx.x >> 5;
  const int l0 = (blockIdx.x & 31) * TLM;
  const int wcol0 = w * 64;
  const float* fbase = features + ((size_t)b * L_ + l0) * D_;

  // A staging mapping: thread -> (row, k-slot); 8 fp32 = 32 B per thread.
  const int ar = tid & 63;
  const int ag = tid >> 6;
  const float* aptr = fbase + ar * D_ + ag * 8;

  // B staging: wave w stages pieces q=0..3 of each 16 KB chunk region.
  _Float16* bhb[2] = {&Bh[0][0][0][0], &Bh[1][0][0][0]};
  _Float16* blb[2] = {&Bl[0][0][0][0], &Bl[1][0][0][0]};
#define STAGE_B(t, buf)                                                     \
  do {                                                                      \
    const size_t roff = (size_t)(t) * 4 * U_ * 8; /* 8192 halves */         \
    _Pragma("unroll") for (int q = 0; q < 4; ++q) {                         \
      const int poff = (w * 4 + q) * 512; /* halves */                      \
      gll16(W1s_hi + roff + poff + lane * 8, bhb[buf] + poff);              \
      gll16(W1s_lo + roff + poff + lane * 8, blb[buf] + poff);              \
    }                                                                       \
  } while (0)

#define CONV_WRITE_A(a0, a1)                                                \
  do {                                                                      \
    union { _Float16 h[8]; float4 f; } H, Lo;                               \
    H.h[0] = (_Float16)a0.x; Lo.h[0] = (_Float16)(a0.x - (float)H.h[0]);    \
    H.h[1] = (_Float16)a0.y; Lo.h[1] = (_Float16)(a0.y - (float)H.h[1]);    \
    H.h[2] = (_Float16)a0.z; Lo.h[2] = (_Float16)(a0.z - (float)H.h[2]);    \
    H.h[3] = (_Float16)a0.w; Lo.h[3] = (_Float16)(a0.w - (float)H.h[3]);    \
    H.h[4] = (_Float16)a1.x; Lo.h[4] = (_Float16)(a1.x - (float)H.h[4]);    \
    H.h[5] = (_Float16)a1.y; Lo.h[5] = (_Float16)(a1.y - (float)H.h[5]);    \
    H.h[6] = (_Float16)a1.z; Lo.h[6] = (_Float16)(a1.z - (float)H.h[6]);    \
    H.h[7] = (_Float16)a1.w; Lo.h[7] = (_Float16)(a1.w - (float)H.h[7]);    \
    *(float4*)&Ah[ag][ar][0] = H.f;                                         \
    *(float4*)&Al[ag][ar][0] = Lo.f;                                        \
  } while (0)

  f32x4 acc[4][4];
#pragma unroll
  for (int mt = 0; mt < 4; ++mt)
#pragma unroll
    for (int nt = 0; nt < 4; ++nt) acc[mt][nt] = (f32x4){0.f, 0.f, 0.f, 0.f};

  // ---- prolog: stage chunk 0 ----
  {
    STAGE_B(0, 0);
    float4 a0 = *(const float4*)(aptr);
    float4 a1 = *(const float4*)(aptr + 4);
    CONV_WRITE_A(a0, a1);
  }
  __syncthreads();  // drains GLL vmcnt + A writes

#pragma unroll
  for (int t = 0; t < NCH; ++t) {
    const int buf = t & 1;
    float4 a0, a1;
    if (t < NCH - 1) {
      // issue next-tile loads before compute (latency hides under MFMA)
      a0 = *(const float4*)(aptr + (t + 1) * BKC);
      a1 = *(const float4*)(aptr + (t + 1) * BKC + 4);
      STAGE_B(t + 1, buf ^ 1);
    }

    // fragments
    half8 ah[4], al[4], bh[4], bl[4];
#pragma unroll
    for (int mt = 0; mt < 4; ++mt) {
      ah[mt] = *(const half8*)&Ah[g][mt * 16 + c][0];
      al[mt] = *(const half8*)&Al[g][mt * 16 + c][0];
    }
#pragma unroll
    for (int nt = 0; nt < 4; ++nt) {
      bh[nt] = *(const half8*)&Bh[buf][g][wcol0 + nt * 16 + c][0];
      bl[nt] = *(const half8*)&Bl[buf][g][wcol0 + nt * 16 + c][0];
    }
    // 3 passes, dependent MFMAs on same acc are 16 instructions apart
#pragma unroll
    for (int nt = 0; nt < 4; ++nt)
#pragma unroll
      for (int mt = 0; mt < 4; ++mt)
        acc[mt][nt] = __builtin_amdgcn_mfma_f32_16x16x32_f16(ah[mt], bh[nt],
                                                             acc[mt][nt], 0, 0, 0);
#pragma unroll
    for (int nt = 0; nt < 4; ++nt)
#pragma unroll
      for (int mt = 0; mt < 4; ++mt)
        acc[mt][nt] = __builtin_amdgcn_mfma_f32_16x16x32_f16(ah[mt], bl[nt],
                                                             acc[mt][nt], 0, 0, 0);
#pragma unroll
    for (int nt = 0; nt < 4; ++nt)
#pragma unroll
      for (int mt = 0; mt < 4; ++mt)
        acc[mt][nt] = __builtin_amdgcn_mfma_f32_16x16x32_f16(al[mt], bh[nt],
                                                             acc[mt][nt], 0, 0, 0);

    __syncthreads();  // frag reads done; drains prefetched loads (vmcnt 0)
    if (t < NCH - 1) {
      CONV_WRITE_A(a0, a1);
      __syncthreads();  // A/B tile t+1 ready
    }
  }

  // epilogue: tanh + V-dot. C layout: col=lane&15, row=(lane>>4)*4+reg.
  float phv[4], vv[4];
#pragma unroll
  for (int nt = 0; nt < 4; ++nt) {
    int col = wcol0 + nt * 16 + c;
    phv[nt] = ph[b * U_ + col];
    vv[nt] = V[col];
  }
#pragma unroll
  for (int mt = 0; mt < 4; ++mt) {
#pragma unroll
    for (int j = 0; j < 4; ++j) {
      float part = 0.f;
#pragma unroll
      for (int nt = 0; nt < 4; ++nt) {
        float x = acc[mt][nt][j] + phv[nt];
        float e = __expf(2.f * x);
        float tnh = 1.f - 2.f * __builtin_amdgcn_rcpf(e + 1.f);  // tanh, inf-safe
        part += tnh * vv[nt];
      }
      part += __shfl_xor(part, 1, 16);
      part += __shfl_xor(part, 2, 16);
      part += __shfl_xor(part, 4, 16);
      part += __shfl_xor(part, 8, 16);
      if (c == 0) red[w][mt * 16 + g * 4 + j] = part;
    }
  }
  __syncthreads();
  if (tid < TLM) {
    logits[b * L_ + l0 + tid] =
        red[0][tid] + red[1][tid] + red[2][tid] + red[3][tid];
  }
#undef STAGE_B
#undef CONV_WRITE_A
}

// ---------------------------------------------------------------------------
// Kernel C: softmax over L per batch; writes attention weights to d_out
// ---------------------------------------------------------------------------
__global__ __launch_bounds__(256) void kc_softmax(
    const float* __restrict__ logits, float* __restrict__ wout) {
  int b = blockIdx.x;
  int tid = threadIdx.x;
  const float* lrow = logits + b * L_;
  float v[8];
  *(float4*)&v[0] = *(const float4*)&lrow[tid * 8];
  *(float4*)&v[4] = *(const float4*)&lrow[tid * 8 + 4];

  float m = v[0];
#pragma unroll
  for (int i = 1; i < 8; ++i) m = fmaxf(m, v[i]);
#pragma unroll
  for (int off = 1; off <= 32; off <<= 1) m = fmaxf(m, __shfl_xor(m, off, 64));
  __shared__ float sm[4];
  if ((tid & 63) == 0) sm[tid >> 6] = m;
  __syncthreads();
  m = fmaxf(fmaxf(sm[0], sm[1]), fmaxf(sm[2], sm[3]));

  float s = 0.f;
#pragma unroll
  for (int i = 0; i < 8; ++i) {
    v[i] = __expf(v[i] - m);
    s += v[i];
  }
#pragma unroll
  for (int off = 1; off <= 32; off <<= 1) s += __shfl_xor(s, off, 64);
  __shared__ float ss[4];
  if ((tid & 63) == 0) ss[tid >> 6] = s;
  __syncthreads();
  s = ss[0] + ss[1] + ss[2] + ss[3];

  float inv = 1.f / s;
#pragma unroll
  for (int i = 0; i < 8; ++i) v[i] *= inv;
  *(float4*)&wout[b * L_ + tid * 8] = *(float4*)&v[0];
  *(float4*)&wout[b * L_ + tid * 8 + 4] = *(float4*)&v[4];
}

// ---------------------------------------------------------------------------
// Kernel D: partials[b][chunk][d] = sum_{l in chunk of 256} w[l]*f[l][d]
// ---------------------------------------------------------------------------
__global__ __launch_bounds__(256) void kd_partial(
    const float* __restrict__ features, const float* __restrict__ w,
    float* __restrict__ partials) {
  int bidx = blockIdx.x;  // B*8
  int b = bidx >> 3;
  int chunk = bidx & 7;
  int tid = threadIdx.x;
  int lq = tid >> 6;
  int dq = tid & 63;
  __shared__ float wsm[256];
  wsm[tid] = w[b * L_ + chunk * 256 + tid];
  __syncthreads();
  const float* fb =
      features + ((size_t)b * L_ + chunk * 256 + lq * 64) * D_ + dq * 4;
  const float* wl = &wsm[lq * 64];
  float4 acc = {0.f, 0.f, 0.f, 0.f};
#pragma unroll 8
  for (int i = 0; i < 64; ++i) {
    float wt = wl[i];
    float4 fv = *(const float4*)(fb + (size_t)i * D_);
    acc.x += wt * fv.x;
    acc.y += wt * fv.y;
    acc.z += wt * fv.z;
    acc.w += wt * fv.w;
  }
  __shared__ float red[4][256];
  *(float4*)&red[lq][dq * 4] = acc;
  __syncthreads();
  float ssum = red[0][tid] + red[1][tid] + red[2][tid] + red[3][tid];
  partials[(size_t)(b * 8 + chunk) * 256 + tid] = ssum;
}

// ---------------------------------------------------------------------------
// Kernel E: context[b][d] = sum_c partials[b][c][d]
// ---------------------------------------------------------------------------
__global__ __launch_bounds__(256) void ke_reduce(
    const float* __restrict__ partials, float* __restrict__ ctx) {
  int b = blockIdx.x;
  int d = threadIdx.x;
  float s = 0.f;
#pragma unroll
  for (int c = 0; c < 8; ++c) s += partials[(size_t)(b * 8 + c) * 256 + d];
  ctx[b * 256 + d] = s;
}

// ---------------------------------------------------------------------------
extern "C" void kernel_launch(void* const* d_in, const int* in_sizes, int n_in,
                              void* d_out, int out_size, void* d_ws,
                              size_t ws_size, hipStream_t stream) {
  const float* features = (const float*)d_in[0];
  const float* hidden = (const float*)d_in[1];
  const float* W1 = (const float*)d_in[2];
  const float* b1 = (const float*)d_in[3];
  const float* W2 = (const float*)d_in[4];
  const float* b2 = (const float*)d_in[5];
  const float* V = (const float*)d_in[6];
  // d_in[7] = bV: softmax shift-invariant, logits not returned -> dropped.

  float* ws = (float*)d_ws;
  float* ph = ws;                              // 32768 floats
  float* logits = ws + 32768;                  // 262144 floats
  float* partials = ws + 32768 + 262144;       // 262144 floats
  _Float16* W1s_hi = (_Float16*)(ws + 557056); // 65536 halves (slot-major)
  _Float16* W1s_lo = W1s_hi + 65536;           // 65536 halves

  float* ctx = (float*)d_out;             // [B, D]
  float* wout = (float*)d_out + B_ * D_;  // [B, L, 1]

  kp_w1split<<<D_ / 8, 256, 0, stream>>>(W1, W1s_hi, W1s_lo);
  ka_proj_h<<<B_, 256, 0, stream>>>(hidden, W2, b1, b2, ph);
  kb_mfma<<<B_ * (L_ / TLM), 256, 0, stream>>>(features, W1s_hi, W1s_lo, ph, V,
                                               logits);
  kc_softmax<<<B_, 256, 0, stream>>>(logits, wout);
  kd_partial<<<B_ * 8, 256, 0, stream>>>(features, wout, partials);
  ke_reduce<<<B_, 256, 0, stream>>>(partials, ctx);
}

// Round 10
// 487.141 us; speedup vs baseline: 1.1090x; 1.1090x over previous
//
#include <hip/hip_runtime.h>
#include <hip/hip_bf16.h>

#define B_ 128
#define L_ 2048
#define D_ 256
#define H_ 512
#define U_ 256

typedef _Float16 half8 __attribute__((ext_vector_type(8)));
typedef float f32x4 __attribute__((ext_vector_type(4)));

// ---------------------------------------------------------------------------
// Kernel P: W1 [D][U] fp32 -> slot-major split halves W1s[slot=k/8][u][k%8]
// x = hi + lo, 22 effective mantissa bits. Chunk t reads slots 4t..4t+3 =
// one contiguous 16 KB region per half.
// ---------------------------------------------------------------------------
__global__ __launch_bounds__(256) void kp_w1split(
    const float* __restrict__ W1, _Float16* __restrict__ hi,
    _Float16* __restrict__ lo) {
  int slot = blockIdx.x;  // D_/8 = 32
  int u = threadIdx.x;
  union { _Float16 h[8]; float4 f; } H, Lo;
#pragma unroll
  for (int j = 0; j < 8; ++j) {
    float x = W1[(slot * 8 + j) * U_ + u];
    _Float16 h = (_Float16)x;
    H.h[j] = h;
    Lo.h[j] = (_Float16)(x - (float)h);
  }
  *(float4*)&hi[((size_t)slot * U_ + u) * 8] = H.f;
  *(float4*)&lo[((size_t)slot * U_ + u) * 8] = Lo.f;
}

// ---------------------------------------------------------------------------
// Kernel A: ph[b][u] = b1[u] + b2[u] + sum_k hidden[b][k] * W2[k][u]
// ---------------------------------------------------------------------------
__global__ __launch_bounds__(256) void ka_proj_h(
    const float* __restrict__ hidden, const float* __restrict__ W2,
    const float* __restrict__ b1, const float* __restrict__ b2,
    float* __restrict__ ph) {
  int b = blockIdx.x;
  int u = threadIdx.x;
  __shared__ float hs[H_];
  for (int k = u; k < H_; k += 256) hs[k] = hidden[b * H_ + k];
  __syncthreads();
  float acc = b1[u] + b2[u];
#pragma unroll 8
  for (int k = 0; k < H_; ++k) acc += hs[k] * W2[k * U_ + u];
  ph[b * U_ + u] = acc;
}

// ---------------------------------------------------------------------------
// Kernel B (MFMA): logits = sum_u tanh(F·W1 + ph) * V
// 512 thr = 8 waves, tile 128 rows x 256 cols; wave (wr=w>>2, wc=w&3) owns
// rows wr*64..+63 x cols wc*64..+63 (M-rep 4, N-rep 4). K chunks of 32.
// Single-buffer LDS 48 KB (2 blocks/CU = 16 waves, the VGPR cap).
// Prefetch t+1 into REGISTERS before MFMA(t); ds_write between barriers
// (T14: HBM/L2 latency hides under MFMA, no LDS double-buffer cost).
// Slot-major LDS [g][row][8] -> all ds accesses conflict-free.
// ---------------------------------------------------------------------------
#define TLM 128
#define BKC 32
#define NCH (D_ / BKC)  // 8 chunks

__global__ __launch_bounds__(512, 4) void kb_mfma(
    const float* __restrict__ features, const _Float16* __restrict__ W1s_hi,
    const _Float16* __restrict__ W1s_lo, const float* __restrict__ ph,
    const float* __restrict__ V, float* __restrict__ logits) {
  __shared__ __align__(16) char smem[49152];  // 48 KB
  _Float16(*Ah)[TLM][8] = (_Float16(*)[TLM][8])(smem);          // 8 KB
  _Float16(*Al)[TLM][8] = (_Float16(*)[TLM][8])(smem + 8192);   // 8 KB
  _Float16* Bh = (_Float16*)(smem + 16384);                     // 16 KB
  _Float16* Bl = (_Float16*)(smem + 32768);                     // 16 KB
  float(*red)[TLM] = (float(*)[TLM])(smem);  // aliases A after final chunk

  const int tid = threadIdx.x;
  const int w = tid >> 6;
  const int lane = tid & 63;
  const int g = lane >> 4;
  const int c = lane & 15;
  const int wr = w >> 2;
  const int wc = w & 3;
  const int b = blockIdx.x >> 4;  // 16 row-tiles per batch
  const int l0 = (blockIdx.x & 15) * TLM;
  const float* fbase = features + ((size_t)b * L_ + l0) * D_;

  // A staging: thread -> (row ar, k-slot ag), 8 fp32 = 32 B contiguous.
  const int ar = tid & 127;
  const int ag = tid >> 7;
  const float* aptr = fbase + (size_t)ar * D_ + ag * 8;

#define CONV_WRITE_A(a0, a1)                                                \
  do {                                                                      \
    union { _Float16 h[8]; float4 f; } Hh, Ll;                              \
    Hh.h[0] = (_Float16)a0.x; Ll.h[0] = (_Float16)(a0.x - (float)Hh.h[0]);  \
    Hh.h[1] = (_Float16)a0.y; Ll.h[1] = (_Float16)(a0.y - (float)Hh.h[1]);  \
    Hh.h[2] = (_Float16)a0.z; Ll.h[2] = (_Float16)(a0.z - (float)Hh.h[2]);  \
    Hh.h[3] = (_Float16)a0.w; Ll.h[3] = (_Float16)(a0.w - (float)Hh.h[3]);  \
    Hh.h[4] = (_Float16)a1.x; Ll.h[4] = (_Float16)(a1.x - (float)Hh.h[4]);  \
    Hh.h[5] = (_Float16)a1.y; Ll.h[5] = (_Float16)(a1.y - (float)Hh.h[5]);  \
    Hh.h[6] = (_Float16)a1.z; Ll.h[6] = (_Float16)(a1.z - (float)Hh.h[6]);  \
    Hh.h[7] = (_Float16)a1.w; Ll.h[7] = (_Float16)(a1.w - (float)Hh.h[7]);  \
    *(float4*)&Ah[ag][ar][0] = Hh.f;                                        \
    *(float4*)&Al[ag][ar][0] = Ll.f;                                        \
  } while (0)

  f32x4 acc[4][4];
#pragma unroll
  for (int mt = 0; mt < 4; ++mt)
#pragma unroll
    for (int nt = 0; nt < 4; ++nt) acc[mt][nt] = (f32x4){0.f, 0.f, 0.f, 0.f};

  // B staging map: idx in [0,1024) -> 16 B at Bh+idx*8 halves (and Bl).
  // Lanes consecutive -> 16 B apart -> conflict-free b128 writes.
  // ---- prolog: stage chunk 0 ----
  {
    float4 a0 = *(const float4*)(aptr);
    float4 a1 = *(const float4*)(aptr + 4);
    float4 h0 = *(const float4*)&W1s_hi[(size_t)tid * 8];
    float4 h1 = *(const float4*)&W1s_hi[(size_t)(tid + 512) * 8];
    float4 q0 = *(const float4*)&W1s_lo[(size_t)tid * 8];
    float4 q1 = *(const float4*)&W1s_lo[(size_t)(tid + 512) * 8];
    CONV_WRITE_A(a0, a1);
    *(float4*)&Bh[(size_t)tid * 8] = h0;
    *(float4*)&Bh[(size_t)(tid + 512) * 8] = h1;
    *(float4*)&Bl[(size_t)tid * 8] = q0;
    *(float4*)&Bl[(size_t)(tid + 512) * 8] = q1;
  }
  __syncthreads();

#pragma unroll
  for (int t = 0; t < NCH; ++t) {
    float4 a0, a1, h0, h1, q0, q1;
    if (t < NCH - 1) {  // issue prefetch loads first: latency under MFMA
      const size_t roff = (size_t)(t + 1) * 8192;  // halves per chunk region
      a0 = *(const float4*)(aptr + (t + 1) * BKC);
      a1 = *(const float4*)(aptr + (t + 1) * BKC + 4);
      h0 = *(const float4*)&W1s_hi[roff + (size_t)tid * 8];
      h1 = *(const float4*)&W1s_hi[roff + (size_t)(tid + 512) * 8];
      q0 = *(const float4*)&W1s_lo[roff + (size_t)tid * 8];
      q1 = *(const float4*)&W1s_lo[roff + (size_t)(tid + 512) * 8];
    }

    // fragments (slot-major, conflict-free)
    half8 ah[4], al[4], bh[4], bl[4];
#pragma unroll
    for (int mt = 0; mt < 4; ++mt) {
      ah[mt] = *(const half8*)&Ah[g][wr * 64 + mt * 16 + c][0];
      al[mt] = *(const half8*)&Al[g][wr * 64 + mt * 16 + c][0];
    }
#pragma unroll
    for (int nt = 0; nt < 4; ++nt) {
      const int u = wc * 64 + nt * 16 + c;
      bh[nt] = *(const half8*)&Bh[((size_t)g * U_ + u) * 8];
      bl[nt] = *(const half8*)&Bl[((size_t)g * U_ + u) * 8];
    }
    // 3 passes; dependent MFMAs on the same acc are 16 instructions apart
#pragma unroll
    for (int nt = 0; nt < 4; ++nt)
#pragma unroll
      for (int mt = 0; mt < 4; ++mt)
        acc[mt][nt] = __builtin_amdgcn_mfma_f32_16x16x32_f16(ah[mt], bh[nt],
                                                             acc[mt][nt], 0, 0, 0);
#pragma unroll
    for (int nt = 0; nt < 4; ++nt)
#pragma unroll
      for (int mt = 0; mt < 4; ++mt)
        acc[mt][nt] = __builtin_amdgcn_mfma_f32_16x16x32_f16(ah[mt], bl[nt],
                                                             acc[mt][nt], 0, 0, 0);
#pragma unroll
    for (int nt = 0; nt < 4; ++nt)
#pragma unroll
      for (int mt = 0; mt < 4; ++mt)
        acc[mt][nt] = __builtin_amdgcn_mfma_f32_16x16x32_f16(al[mt], bh[nt],
                                                             acc[mt][nt], 0, 0, 0);

    __syncthreads();  // everyone done reading tile t
    if (t < NCH - 1) {
      CONV_WRITE_A(a0, a1);  // pure LDS writes: loads landed during MFMA
      *(float4*)&Bh[(size_t)tid * 8] = h0;
      *(float4*)&Bh[(size_t)(tid + 512) * 8] = h1;
      *(float4*)&Bl[(size_t)tid * 8] = q0;
      *(float4*)&Bl[(size_t)(tid + 512) * 8] = q1;
      __syncthreads();  // tile t+1 ready
    }
  }

  // epilogue: tanh + V-dot. C layout: col=lane&15, row=(lane>>4)*4+reg.
  float phv[4], vv[4];
#pragma unroll
  for (int nt = 0; nt < 4; ++nt) {
    int col = wc * 64 + nt * 16 + c;
    phv[nt] = ph[b * U_ + col];
    vv[nt] = V[col];
  }
#pragma unroll
  for (int mt = 0; mt < 4; ++mt) {
#pragma unroll
    for (int j = 0; j < 4; ++j) {
      float part = 0.f;
#pragma unroll
      for (int nt = 0; nt < 4; ++nt) {
        float x = acc[mt][nt][j] + phv[nt];
        float e = __expf(2.f * x);
        float tnh = 1.f - 2.f * __builtin_amdgcn_rcpf(e + 1.f);  // tanh, inf-safe
        part += tnh * vv[nt];
      }
      part += __shfl_xor(part, 1, 16);
      part += __shfl_xor(part, 2, 16);
      part += __shfl_xor(part, 4, 16);
      part += __shfl_xor(part, 8, 16);
      // red aliases A: safe, all frag reads are behind the last barrier
      if (c == 0) red[wc][wr * 64 + mt * 16 + g * 4 + j] = part;
    }
  }
  __syncthreads();
  if (tid < TLM) {
    logits[b * L_ + l0 + tid] =
        red[0][tid] + red[1][tid] + red[2][tid] + red[3][tid];
  }
#undef CONV_WRITE_A
}

// ---------------------------------------------------------------------------
// Kernel C: softmax over L per batch; writes attention weights to d_out
// ---------------------------------------------------------------------------
__global__ __launch_bounds__(256) void kc_softmax(
    const float* __restrict__ logits, float* __restrict__ wout) {
  int b = blockIdx.x;
  int tid = threadIdx.x;
  const float* lrow = logits + b * L_;
  float v[8];
  *(float4*)&v[0] = *(const float4*)&lrow[tid * 8];
  *(float4*)&v[4] = *(const float4*)&lrow[tid * 8 + 4];

  float m = v[0];
#pragma unroll
  for (int i = 1; i < 8; ++i) m = fmaxf(m, v[i]);
#pragma unroll
  for (int off = 1; off <= 32; off <<= 1) m = fmaxf(m, __shfl_xor(m, off, 64));
  __shared__ float sm[4];
  if ((tid & 63) == 0) sm[tid >> 6] = m;
  __syncthreads();
  m = fmaxf(fmaxf(sm[0], sm[1]), fmaxf(sm[2], sm[3]));

  float s = 0.f;
#pragma unroll
  for (int i = 0; i < 8; ++i) {
    v[i] = __expf(v[i] - m);
    s += v[i];
  }
#pragma unroll
  for (int off = 1; off <= 32; off <<= 1) s += __shfl_xor(s, off, 64);
  __shared__ float ss[4];
  if ((tid & 63) == 0) ss[tid >> 6] = s;
  __syncthreads();
  s = ss[0] + ss[1] + ss[2] + ss[3];

  float inv = 1.f / s;
#pragma unroll
  for (int i = 0; i < 8; ++i) v[i] *= inv;
  *(float4*)&wout[b * L_ + tid * 8] = *(float4*)&v[0];
  *(float4*)&wout[b * L_ + tid * 8 + 4] = *(float4*)&v[4];
}

// ---------------------------------------------------------------------------
// Kernel D: partials[b][chunk][d] = sum_{l in chunk of 256} w[l]*f[l][d]
// ---------------------------------------------------------------------------
__global__ __launch_bounds__(256) void kd_partial(
    const float* __restrict__ features, const float* __restrict__ w,
    float* __restrict__ partials) {
  int bidx = blockIdx.x;  // B*8
  int b = bidx >> 3;
  int chunk = bidx & 7;
  int tid = threadIdx.x;
  int lq = tid >> 6;
  int dq = tid & 63;
  __shared__ float wsm[256];
  wsm[tid] = w[b * L_ + chunk * 256 + tid];
  __syncthreads();
  const float* fb =
      features + ((size_t)b * L_ + chunk * 256 + lq * 64) * D_ + dq * 4;
  const float* wl = &wsm[lq * 64];
  float4 acc = {0.f, 0.f, 0.f, 0.f};
#pragma unroll 8
  for (int i = 0; i < 64; ++i) {
    float wt = wl[i];
    float4 fv = *(const float4*)(fb + (size_t)i * D_);
    acc.x += wt * fv.x;
    acc.y += wt * fv.y;
    acc.z += wt * fv.z;
    acc.w += wt * fv.w;
  }
  __shared__ float red[4][256];
  *(float4*)&red[lq][dq * 4] = acc;
  __syncthreads();
  float ssum = red[0][tid] + red[1][tid] + red[2][tid] + red[3][tid];
  partials[(size_t)(b * 8 + chunk) * 256 + tid] = ssum;
}

// ---------------------------------------------------------------------------
// Kernel E: context[b][d] = sum_c partials[b][c][d]
// ---------------------------------------------------------------------------
__global__ __launch_bounds__(256) void ke_reduce(
    const float* __restrict__ partials, float* __restrict__ ctx) {
  int b = blockIdx.x;
  int d = threadIdx.x;
  float s = 0.f;
#pragma unroll
  for (int c = 0; c < 8; ++c) s += partials[(size_t)(b * 8 + c) * 256 + d];
  ctx[b * 256 + d] = s;
}

// ---------------------------------------------------------------------------
extern "C" void kernel_launch(void* const* d_in, const int* in_sizes, int n_in,
                              void* d_out, int out_size, void* d_ws,
                              size_t ws_size, hipStream_t stream) {
  const float* features = (const float*)d_in[0];
  const float* hidden = (const float*)d_in[1];
  const float* W1 = (const float*)d_in[2];
  const float* b1 = (const float*)d_in[3];
  const float* W2 = (const float*)d_in[4];
  const float* b2 = (const float*)d_in[5];
  const float* V = (const float*)d_in[6];
  // d_in[7] = bV: softmax shift-invariant, logits not returned -> dropped.

  float* ws = (float*)d_ws;
  float* ph = ws;                              // 32768 floats
  float* logits = ws + 32768;                  // 262144 floats
  float* partials = ws + 32768 + 262144;       // 262144 floats
  _Float16* W1s_hi = (_Float16*)(ws + 557056); // 65536 halves (slot-major)
  _Float16* W1s_lo = W1s_hi + 65536;           // 65536 halves

  float* ctx = (float*)d_out;             // [B, D]
  float* wout = (float*)d_out + B_ * D_;  // [B, L, 1]

  kp_w1split<<<D_ / 8, 256, 0, stream>>>(W1, W1s_hi, W1s_lo);
  ka_proj_h<<<B_, 256, 0, stream>>>(hidden, W2, b1, b2, ph);
  kb_mfma<<<B_ * (L_ / TLM), 512, 0, stream>>>(features, W1s_hi, W1s_lo, ph, V,
                                               logits);
  kc_softmax<<<B_, 256, 0, stream>>>(logits, wout);
  kd_partial<<<B_ * 8, 256, 0, stream>>>(features, wout, partials);
  ke_reduce<<<B_, 256, 0, stream>>>(partials, ctx);
}

// Round 11
// 486.370 us; speedup vs baseline: 1.1108x; 1.0016x over previous
//
#include <hip/hip_runtime.h>
#include <hip/hip_bf16.h>

#define B_ 128
#define L_ 2048
#define D_ 256
#define H_ 512
#define U_ 256

typedef _Float16 half8 __attribute__((ext_vector_type(8)));
typedef float f32x4 __attribute__((ext_vector_type(4)));

// ---------------------------------------------------------------------------
// Kernel PA (fused): blocks 0..31: W1 split; blocks 32..159: proj_h.
// W1 [D][U] fp32 -> slot-major halves W1s[slot=k/8][u][k%8] (hi+lo).
// B = hi+lo is consumed exactly (2 MFMA passes vs A-hi), so B carries
// ~22 mantissa bits; A is fp16-hi only (error al·b lands ~3e-5 in outputs,
// below the kd summation-order floor of 1.2e-4 — verified invisible).
// ---------------------------------------------------------------------------
__global__ __launch_bounds__(256) void kpa_prep(
    const float* __restrict__ W1, _Float16* __restrict__ hi,
    _Float16* __restrict__ lo, const float* __restrict__ hidden,
    const float* __restrict__ W2, const float* __restrict__ b1,
    const float* __restrict__ b2, float* __restrict__ ph) {
  __shared__ float hs[H_];
  if (blockIdx.x < 32) {
    int slot = blockIdx.x;  // D_/8 = 32
    int u = threadIdx.x;
    union { _Float16 h[8]; float4 f; } H, Lo;
#pragma unroll
    for (int j = 0; j < 8; ++j) {
      float x = W1[(slot * 8 + j) * U_ + u];
      _Float16 h = (_Float16)x;
      H.h[j] = h;
      Lo.h[j] = (_Float16)(x - (float)h);
    }
    *(float4*)&hi[((size_t)slot * U_ + u) * 8] = H.f;
    *(float4*)&lo[((size_t)slot * U_ + u) * 8] = Lo.f;
  } else {
    int b = blockIdx.x - 32;
    int u = threadIdx.x;
    for (int k = u; k < H_; k += 256) hs[k] = hidden[b * H_ + k];
    __syncthreads();
    float acc = b1[u] + b2[u];
#pragma unroll 8
    for (int k = 0; k < H_; ++k) acc += hs[k] * W2[k * U_ + u];
    ph[b * U_ + u] = acc;
  }
}

// ---------------------------------------------------------------------------
// Kernel B (MFMA, 2-pass): logits = sum_u tanh(F·W1 + ph) * V
// 512 thr = 8 waves, tile 128 rows x 256 cols; wave (wr,wc) owns 64x64.
// Passes: ah·bh + ah·bl (A fp16-hi only). K chunks of 32.
// LDS 40 KB single-buffer -> 2+ blocks/CU; reg-prefetch t+1 before MFMA(t),
// ds_write between the two barriers (T14). Slot-major layout: conflict-free
// (measured 0 conflicts, round 7).
// ---------------------------------------------------------------------------
#define TLM 128
#define BKC 32
#define NCH (D_ / BKC)  // 8 chunks

__global__ __launch_bounds__(512, 4) void kb_mfma(
    const float* __restrict__ features, const _Float16* __restrict__ W1s_hi,
    const _Float16* __restrict__ W1s_lo, const float* __restrict__ ph,
    const float* __restrict__ V, float* __restrict__ logits) {
  __shared__ __align__(16) char smem[40960];  // 40 KB
  _Float16(*Ah)[TLM][8] = (_Float16(*)[TLM][8])(smem);  // 8 KB
  _Float16* Bh = (_Float16*)(smem + 8192);              // 16 KB
  _Float16* Bl = (_Float16*)(smem + 24576);             // 16 KB
  float(*red)[TLM] = (float(*)[TLM])(smem);  // aliases Ah after final chunk

  const int tid = threadIdx.x;
  const int w = tid >> 6;
  const int lane = tid & 63;
  const int g = lane >> 4;
  const int c = lane & 15;
  const int wr = w >> 2;
  const int wc = w & 3;
  const int b = blockIdx.x >> 4;  // 16 row-tiles per batch
  const int l0 = (blockIdx.x & 15) * TLM;
  const float* fbase = features + ((size_t)b * L_ + l0) * D_;

  // A staging: thread -> (row ar, k-slot ag), 8 fp32 = 32 B contiguous.
  const int ar = tid & 127;
  const int ag = tid >> 7;
  const float* aptr = fbase + (size_t)ar * D_ + ag * 8;

#define CONV_WRITE_A(a0, a1)                                                \
  do {                                                                      \
    union { _Float16 h[8]; float4 f; } Hh;                                  \
    Hh.h[0] = (_Float16)a0.x;                                               \
    Hh.h[1] = (_Float16)a0.y;                                               \
    Hh.h[2] = (_Float16)a0.z;                                               \
    Hh.h[3] = (_Float16)a0.w;                                               \
    Hh.h[4] = (_Float16)a1.x;                                               \
    Hh.h[5] = (_Float16)a1.y;                                               \
    Hh.h[6] = (_Float16)a1.z;                                               \
    Hh.h[7] = (_Float16)a1.w;                                               \
    *(float4*)&Ah[ag][ar][0] = Hh.f;                                        \
  } while (0)

  f32x4 acc[4][4];
#pragma unroll
  for (int mt = 0; mt < 4; ++mt)
#pragma unroll
    for (int nt = 0; nt < 4; ++nt) acc[mt][nt] = (f32x4){0.f, 0.f, 0.f, 0.f};

  // ---- prolog: stage chunk 0 ----
  {
    float4 a0 = *(const float4*)(aptr);
    float4 a1 = *(const float4*)(aptr + 4);
    float4 h0 = *(const float4*)&W1s_hi[(size_t)tid * 8];
    float4 h1 = *(const float4*)&W1s_hi[(size_t)(tid + 512) * 8];
    float4 q0 = *(const float4*)&W1s_lo[(size_t)tid * 8];
    float4 q1 = *(const float4*)&W1s_lo[(size_t)(tid + 512) * 8];
    CONV_WRITE_A(a0, a1);
    *(float4*)&Bh[(size_t)tid * 8] = h0;
    *(float4*)&Bh[(size_t)(tid + 512) * 8] = h1;
    *(float4*)&Bl[(size_t)tid * 8] = q0;
    *(float4*)&Bl[(size_t)(tid + 512) * 8] = q1;
  }
  __syncthreads();

#pragma unroll
  for (int t = 0; t < NCH; ++t) {
    float4 a0, a1, h0, h1, q0, q1;
    if (t < NCH - 1) {  // issue prefetch loads first: latency under MFMA
      const size_t roff = (size_t)(t + 1) * 8192;  // halves per chunk region
      a0 = *(const float4*)(aptr + (t + 1) * BKC);
      a1 = *(const float4*)(aptr + (t + 1) * BKC + 4);
      h0 = *(const float4*)&W1s_hi[roff + (size_t)tid * 8];
      h1 = *(const float4*)&W1s_hi[roff + (size_t)(tid + 512) * 8];
      q0 = *(const float4*)&W1s_lo[roff + (size_t)tid * 8];
      q1 = *(const float4*)&W1s_lo[roff + (size_t)(tid + 512) * 8];
    }

    // fragments (slot-major, conflict-free)
    half8 ah[4], bh[4], bl[4];
#pragma unroll
    for (int mt = 0; mt < 4; ++mt)
      ah[mt] = *(const half8*)&Ah[g][wr * 64 + mt * 16 + c][0];
#pragma unroll
    for (int nt = 0; nt < 4; ++nt) {
      const int u = wc * 64 + nt * 16 + c;
      bh[nt] = *(const half8*)&Bh[((size_t)g * U_ + u) * 8];
      bl[nt] = *(const half8*)&Bl[((size_t)g * U_ + u) * 8];
    }
    // 2 passes; dependent MFMAs on the same acc are 16 instructions apart
#pragma unroll
    for (int nt = 0; nt < 4; ++nt)
#pragma unroll
      for (int mt = 0; mt < 4; ++mt)
        acc[mt][nt] = __builtin_amdgcn_mfma_f32_16x16x32_f16(ah[mt], bh[nt],
                                                             acc[mt][nt], 0, 0, 0);
#pragma unroll
    for (int nt = 0; nt < 4; ++nt)
#pragma unroll
      for (int mt = 0; mt < 4; ++mt)
        acc[mt][nt] = __builtin_amdgcn_mfma_f32_16x16x32_f16(ah[mt], bl[nt],
                                                             acc[mt][nt], 0, 0, 0);

    __syncthreads();  // everyone done reading tile t
    if (t < NCH - 1) {
      CONV_WRITE_A(a0, a1);  // pure LDS writes: loads landed during MFMA
      *(float4*)&Bh[(size_t)tid * 8] = h0;
      *(float4*)&Bh[(size_t)(tid + 512) * 8] = h1;
      *(float4*)&Bl[(size_t)tid * 8] = q0;
      *(float4*)&Bl[(size_t)(tid + 512) * 8] = q1;
      __syncthreads();  // tile t+1 ready
    }
  }

  // epilogue: tanh + V-dot. C layout: col=lane&15, row=(lane>>4)*4+reg.
  float phv[4], vv[4];
#pragma unroll
  for (int nt = 0; nt < 4; ++nt) {
    int col = wc * 64 + nt * 16 + c;
    phv[nt] = ph[b * U_ + col];
    vv[nt] = V[col];
  }
#pragma unroll
  for (int mt = 0; mt < 4; ++mt) {
#pragma unroll
    for (int j = 0; j < 4; ++j) {
      float part = 0.f;
#pragma unroll
      for (int nt = 0; nt < 4; ++nt) {
        float x = acc[mt][nt][j] + phv[nt];
        float e = __expf(2.f * x);
        float tnh = 1.f - 2.f * __builtin_amdgcn_rcpf(e + 1.f);  // tanh, inf-safe
        part += tnh * vv[nt];
      }
      part += __shfl_xor(part, 1, 16);
      part += __shfl_xor(part, 2, 16);
      part += __shfl_xor(part, 4, 16);
      part += __shfl_xor(part, 8, 16);
      // red aliases Ah: safe, all frag reads are behind the last barrier
      if (c == 0) red[wc][wr * 64 + mt * 16 + g * 4 + j] = part;
    }
  }
  __syncthreads();
  if (tid < TLM) {
    logits[b * L_ + l0 + tid] =
        red[0][tid] + red[1][tid] + red[2][tid] + red[3][tid];
  }
#undef CONV_WRITE_A
}

// ---------------------------------------------------------------------------
// Kernel C: softmax over L per batch; writes attention weights to d_out
// ---------------------------------------------------------------------------
__global__ __launch_bounds__(256) void kc_softmax(
    const float* __restrict__ logits, float* __restrict__ wout) {
  int b = blockIdx.x;
  int tid = threadIdx.x;
  const float* lrow = logits + b * L_;
  float v[8];
  *(float4*)&v[0] = *(const float4*)&lrow[tid * 8];
  *(float4*)&v[4] = *(const float4*)&lrow[tid * 8 + 4];

  float m = v[0];
#pragma unroll
  for (int i = 1; i < 8; ++i) m = fmaxf(m, v[i]);
#pragma unroll
  for (int off = 1; off <= 32; off <<= 1) m = fmaxf(m, __shfl_xor(m, off, 64));
  __shared__ float sm[4];
  if ((tid & 63) == 0) sm[tid >> 6] = m;
  __syncthreads();
  m = fmaxf(fmaxf(sm[0], sm[1]), fmaxf(sm[2], sm[3]));

  float s = 0.f;
#pragma unroll
  for (int i = 0; i < 8; ++i) {
    v[i] = __expf(v[i] - m);
    s += v[i];
  }
#pragma unroll
  for (int off = 1; off <= 32; off <<= 1) s += __shfl_xor(s, off, 64);
  __shared__ float ss[4];
  if ((tid & 63) == 0) ss[tid >> 6] = s;
  __syncthreads();
  s = ss[0] + ss[1] + ss[2] + ss[3];

  float inv = 1.f / s;
#pragma unroll
  for (int i = 0; i < 8; ++i) v[i] *= inv;
  *(float4*)&wout[b * L_ + tid * 8] = *(float4*)&v[0];
  *(float4*)&wout[b * L_ + tid * 8 + 4] = *(float4*)&v[4];
}

// ---------------------------------------------------------------------------
// Kernel D: partials[b][chunk][d] = sum_{l in chunk of 256} w[l]*f[l][d]
// ---------------------------------------------------------------------------
__global__ __launch_bounds__(256) void kd_partial(
    const float* __restrict__ features, const float* __restrict__ w,
    float* __restrict__ partials) {
  int bidx = blockIdx.x;  // B*8
  int b = bidx >> 3;
  int chunk = bidx & 7;
  int tid = threadIdx.x;
  int lq = tid >> 6;
  int dq = tid & 63;
  __shared__ float wsm[256];
  wsm[tid] = w[b * L_ + chunk * 256 + tid];
  __syncthreads();
  const float* fb =
      features + ((size_t)b * L_ + chunk * 256 + lq * 64) * D_ + dq * 4;
  const float* wl = &wsm[lq * 64];
  float4 acc = {0.f, 0.f, 0.f, 0.f};
#pragma unroll 8
  for (int i = 0; i < 64; ++i) {
    float wt = wl[i];
    float4 fv = *(const float4*)(fb + (size_t)i * D_);
    acc.x += wt * fv.x;
    acc.y += wt * fv.y;
    acc.z += wt * fv.z;
    acc.w += wt * fv.w;
  }
  __shared__ float red[4][256];
  *(float4*)&red[lq][dq * 4] = acc;
  __syncthreads();
  float ssum = red[0][tid] + red[1][tid] + red[2][tid] + red[3][tid];
  partials[(size_t)(b * 8 + chunk) * 256 + tid] = ssum;
}

// ---------------------------------------------------------------------------
// Kernel E: context[b][d] = sum_c partials[b][c][d]
// ---------------------------------------------------------------------------
__global__ __launch_bounds__(256) void ke_reduce(
    const float* __restrict__ partials, float* __restrict__ ctx) {
  int b = blockIdx.x;
  int d = threadIdx.x;
  float s = 0.f;
#pragma unroll
  for (int c = 0; c < 8; ++c) s += partials[(size_t)(b * 8 + c) * 256 + d];
  ctx[b * 256 + d] = s;
}

// ---------------------------------------------------------------------------
extern "C" void kernel_launch(void* const* d_in, const int* in_sizes, int n_in,
                              void* d_out, int out_size, void* d_ws,
                              size_t ws_size, hipStream_t stream) {
  const float* features = (const float*)d_in[0];
  const float* hidden = (const float*)d_in[1];
  const float* W1 = (const float*)d_in[2];
  const float* b1 = (const float*)d_in[3];
  const float* W2 = (const float*)d_in[4];
  const float* b2 = (const float*)d_in[5];
  const float* V = (const float*)d_in[6];
  // d_in[7] = bV: softmax shift-invariant, logits not returned -> dropped.

  float* ws = (float*)d_ws;
  float* ph = ws;                              // 32768 floats
  float* logits = ws + 32768;                  // 262144 floats
  float* partials = ws + 32768 + 262144;       // 262144 floats
  _Float16* W1s_hi = (_Float16*)(ws + 557056); // 65536 halves (slot-major)
  _Float16* W1s_lo = W1s_hi + 65536;           // 65536 halves

  float* ctx = (float*)d_out;             // [B, D]
  float* wout = (float*)d_out + B_ * D_;  // [B, L, 1]

  kpa_prep<<<32 + B_, 256, 0, stream>>>(W1, W1s_hi, W1s_lo, hidden, W2, b1, b2,
                                        ph);
  kb_mfma<<<B_ * (L_ / TLM), 512, 0, stream>>>(features, W1s_hi, W1s_lo, ph, V,
                                               logits);
  kc_softmax<<<B_, 256, 0, stream>>>(logits, wout);
  kd_partial<<<B_ * 8, 256, 0, stream>>>(features, wout, partials);
  ke_reduce<<<B_, 256, 0, stream>>>(partials, ctx);
}